// Round 5
// baseline (2045.472 us; speedup 1.0000x reference)
//
#include <hip/hip_runtime.h>
#include <hip/hip_bf16.h>

typedef unsigned short ushort_t;
typedef unsigned int   uint_t;
typedef __attribute__((ext_vector_type(8))) short  short8;   // 8 bf16 (4 VGPR)
typedef __attribute__((ext_vector_type(4))) float  floatx4;  // MFMA acc

#define B_    2
#define R_    8192
#define HW_   256
#define S_    64
#define NRAYS (B_*R_)
#define PLANE_ELEMS ((size_t)64*HW_*HW_)
#define TRP_ELEMS   ((size_t)HW_*HW_*64)
#define WS_PLANES_BYTES (6ull*B_*TRP_ELEMS*2)   /* 100,663,296 */
#define NW_US 10240    /* weight ushorts: 8192 mlp + 2048 head */
#define WV 4           /* waves (rays) per block */

__device__ __forceinline__ float bflo(uint_t u){ union{uint_t i;float f;} v; v.i = u << 16;         return v.f; }
__device__ __forceinline__ float bfhi(uint_t u){ union{uint_t i;float f;} v; v.i = u & 0xffff0000u; return v.f; }
__device__ __forceinline__ float sp(float x){ return fmaxf(x, 0.f) + __logf(1.f + __expf(-fabsf(x))); }
__device__ __forceinline__ ushort_t f2bf(float f){
    union{float f;uint_t u;} v; v.f = f;
    uint_t r = v.u + 0x7fffu + ((v.u >> 16) & 1u);   // RTNE
    return (ushort_t)(r >> 16);
}

// ---------------- Kernel A: transpose+quantize planes [C,H,W]f32 -> [H,W,C]bf16 ----------------
__global__ __launch_bounds__(256) void tr_planes(
    const float* __restrict__ p0, const float* __restrict__ p1, const float* __restrict__ p2,
    const float* __restrict__ p3, const float* __restrict__ p4, const float* __restrict__ p5,
    ushort_t* __restrict__ outp)
{
    const int blk = blockIdx.x;
    const int y = blk & 255, b = (blk >> 8) & 1, p = blk >> 9;
    const float* src = (p==0)?p0:(p==1)?p1:(p==2)?p2:(p==3)?p3:(p==4)?p4:p5;
    src += (size_t)b*PLANE_ELEMS + (size_t)y*HW_ + threadIdx.x;
    ushort_t* dst = outp + (size_t)(p*2+b)*TRP_ELEMS + ((size_t)y*HW_ + threadIdx.x)*64;

    __attribute__((aligned(16))) ushort_t tmp[64];
#pragma unroll
    for (int c = 0; c < 64; ++c)
        tmp[c] = f2bf(src[(size_t)c*HW_*HW_]);
#pragma unroll
    for (int k = 0; k < 8; ++k)
        reinterpret_cast<uint4*>(dst)[k] = reinterpret_cast<const uint4*>(tmp)[k];
}

// ---------------- Kernel A2: weights -> bf16, transposed for B-fragments ----------------
// dst layout (ushorts): [0,8192): Wt[l][o][c];  [8192,10240): head[n][c]:
//   n<16: w_col col n;  n==16: w_opacity;  n in 17..31: 0
__global__ __launch_bounds__(256) void prep_weights(
    const float* __restrict__ mlp_w, const float* __restrict__ w_op,
    const float* __restrict__ w_col, ushort_t* __restrict__ dst)
{
    int i = blockIdx.x*256 + threadIdx.x;
    if (i >= NW_US) return;
    float v;
    if (i < 8192) {
        int l = i >> 12, o = (i >> 6) & 63, c = i & 63;
        v = mlp_w[l*4096 + c*64 + o];
    } else {
        int j = i - 8192, n = j >> 6, c = j & 63;
        v = (n < 16) ? w_col[c*16 + n] : (n == 16 ? w_op[c] : 0.f);
    }
    dst[i] = f2bf(v);
}

// ---------------- Kernel B: render (1 wave = 1 ray; MFMA MLP) ----------------
// R4: mlp_layer MUST preload all A-fragments (af[8]) before any stH write —
// R3 removed the preload and the layer read its own half-written output
// (absmax 0.60). Head split + plain __launch_bounds__(256) kept from R3.
__global__ __launch_bounds__(256) void render(
    const float* __restrict__ rays, const float* __restrict__ centers,
    const float* __restrict__ enc,  const float* __restrict__ nearp, const float* __restrict__ farp,
    const float* __restrict__ mlp_b, const float* __restrict__ b_op,
    const float* __restrict__ b_col, const float* __restrict__ bgc,
    const ushort_t* __restrict__ trp, const ushort_t* __restrict__ wq,
    float* __restrict__ out)
{
    __shared__ ushort_t A_lds[WV][4096];     // 64 rows x 128B, XOR-swizzled 16B slots
    __shared__ float    sd_lds[WV][64];
    __shared__ float    w_lds [WV][64];

    const int wv = threadIdx.x >> 6, lane = threadIdx.x & 63;
    const int gray = blockIdx.x*WV + wv;
    const int b = gray >> 13;
    ushort_t* A = &A_lds[wv][0];

    const float nr = nearp[gray], fr = farp[gray];
    const float rdx = rays[gray*3+0], rdy = rays[gray*3+1], rdz = rays[gray*3+2];
    const float rox = centers[gray*3+0], roy = centers[gray*3+1], roz = centers[gray*3+2];
    const float delta = (fr - nr) * (1.f/S_);
    const float t  = nr + (fr - nr) * ((lane + 0.5f) * (1.f/S_));
    const float px = rox + t*rdx, py = roy + t*rdy, pz = roz + t*rdz;

    // bilinear prep (shared by density & color planes: same pts)
    int pos[3]; float a00[3], a01[3], a10[3], a11[3];
    {
        float us[3] = {px, py, pz};
        float vs[3] = {py, pz, px};
#pragma unroll
        for (int p = 0; p < 3; ++p) {
            float x = (fminf(fmaxf(us[p],-1.f),1.f) + 1.f) * 127.5f;
            float y = (fminf(fmaxf(vs[p],-1.f),1.f) + 1.f) * 127.5f;
            int x0 = (int)floorf(x); x0 = x0 < 0 ? 0 : (x0 > 254 ? 254 : x0);
            int y0 = (int)floorf(y); y0 = y0 < 0 ? 0 : (y0 > 254 ? 254 : y0);
            float wx = x - (float)x0, wy = y - (float)y0;
            pos[p] = y0*HW_ + x0;
            a00[p] = (1.f-wx)*(1.f-wy); a01[p] = wx*(1.f-wy);
            a10[p] = (1.f-wx)*wy;       a11[p] = wx*wy;
        }
    }

    // gather 3 planes into this lane's A row (m = lane), bf16, swizzled
    auto gather3 = [&](int pbase, const float* encrow) {
        const ushort_t* tb[3];
#pragma unroll
        for (int p = 0; p < 3; ++p)
            tb[p] = trp + (size_t)((pbase+p)*2 + b)*TRP_ELEMS + (size_t)pos[p]*64;
#pragma unroll
        for (int c8 = 0; c8 < 8; ++c8) {
            float acc[8] = {0,0,0,0,0,0,0,0};
#pragma unroll
            for (int p = 0; p < 3; ++p) {
                const ushort_t* q = tb[p] + c8*8;
                union { uint4 v; uint_t u[4]; } q00, q01, q10, q11;
                q00.v = *reinterpret_cast<const uint4*>(q);
                q01.v = *reinterpret_cast<const uint4*>(q + 64);
                q10.v = *reinterpret_cast<const uint4*>(q + 64*HW_);
                q11.v = *reinterpret_cast<const uint4*>(q + 64*HW_ + 64);
#pragma unroll
                for (int j = 0; j < 4; ++j) {
                    acc[2*j]   += a00[p]*bflo(q00.u[j]) + a01[p]*bflo(q01.u[j])
                                + a10[p]*bflo(q10.u[j]) + a11[p]*bflo(q11.u[j]);
                    acc[2*j+1] += a00[p]*bfhi(q00.u[j]) + a01[p]*bfhi(q01.u[j])
                                + a10[p]*bfhi(q10.u[j]) + a11[p]*bfhi(q11.u[j]);
                }
            }
            if (encrow) {
                float4 e0 = *reinterpret_cast<const float4*>(encrow + c8*8);
                float4 e1 = *reinterpret_cast<const float4*>(encrow + c8*8 + 4);
                acc[0]+=e0.x; acc[1]+=e0.y; acc[2]+=e0.z; acc[3]+=e0.w;
                acc[4]+=e1.x; acc[5]+=e1.y; acc[6]+=e1.z; acc[7]+=e1.w;
            }
            __attribute__((aligned(16))) ushort_t pk[8];
#pragma unroll
            for (int j = 0; j < 8; ++j) pk[j] = f2bf(acc[j]);
            *reinterpret_cast<uint4*>(reinterpret_cast<char*>(A) + lane*128 + ((c8*16) ^ ((lane&7)<<4)))
                = *reinterpret_cast<const uint4*>(pk);
        }
    };

    // A-fragment load: lane holds row (lane&15) of tile mi, k = kt*32 + (lane>>4)*8 + j
    auto ldfrag = [&](int mi, int kt) -> short8 {
        int m  = mi*16 + (lane&15);
        int cb = (kt*64 + ((lane>>4)*16)) ^ ((m&7)<<4);
        return *reinterpret_cast<const short8*>(reinterpret_cast<const char*>(A) + m*128 + cb);
    };
    // B-fragment: lane holds col (lane&15) of tile nt, k = kt*32 + (lane>>4)*8 + j
    auto ldbfrag = [&](const ushort_t* wrow, int nt, int kt) -> short8 {
        return *reinterpret_cast<const short8*>(wrow + (nt*16 + (lane&15))*64 + kt*32 + (lane>>4)*8);
    };
    // write H value (bf16) at [m][n], swizzled
    auto stH = [&](int m, int n, float v) {
        A[(m*128 + ((n*2) ^ ((m&7)<<4))) >> 1] = f2bf(v);
    };

    // one MLP layer: A(bf16 in LDS) @ Wt -> softplus -> back into A.
    // af[8] preload is a CORRECTNESS requirement: all reads of A must complete
    // before the nt-loop's stH writes overwrite A in place.
    auto mlp_layer = [&](const ushort_t* wrow, const float* bias) {
        short8 af[8];
#pragma unroll
        for (int mi = 0; mi < 4; ++mi)
#pragma unroll
            for (int kt = 0; kt < 2; ++kt) af[mi*2+kt] = ldfrag(mi, kt);
#pragma unroll
        for (int nt = 0; nt < 4; ++nt) {
            short8 b0 = ldbfrag(wrow, nt, 0);
            short8 b1 = ldbfrag(wrow, nt, 1);
            floatx4 acc[4];
#pragma unroll
            for (int mi = 0; mi < 4; ++mi) {
                acc[mi] = (floatx4){0.f,0.f,0.f,0.f};
                acc[mi] = __builtin_amdgcn_mfma_f32_16x16x32_bf16(af[mi*2+0], b0, acc[mi], 0, 0, 0);
                acc[mi] = __builtin_amdgcn_mfma_f32_16x16x32_bf16(af[mi*2+1], b1, acc[mi], 0, 0, 0);
            }
            const int n = nt*16 + (lane&15);
            const float bc = bias[n];
#pragma unroll
            for (int mi = 0; mi < 4; ++mi)
#pragma unroll
                for (int r = 0; r < 4; ++r) {
                    int m = mi*16 + (lane>>4)*4 + r;
                    stH(m, n, sp(acc[mi][r] + bc));
                }
        }
    };

    // ---- pipeline ----
    gather3(0, nullptr);                 // density features -> A
    mlp_layer(wq,        mlp_b);         // layer 1
    mlp_layer(wq + 4096, mlp_b + 64);    // layer 2  (A now holds h)

    const ushort_t* whead = wq + 8192;

    // sigma head: h @ [w_op | 0...]  (nt=1 tile of head region; col 16 = w_op)
    // Heads only READ A — no preload needed.
    {
        short8 b0 = ldbfrag(whead, 1, 0);
        short8 b1 = ldbfrag(whead, 1, 1);
        floatx4 accS[4];
#pragma unroll
        for (int mi = 0; mi < 4; ++mi) {
            accS[mi] = (floatx4){0.f,0.f,0.f,0.f};
            accS[mi] = __builtin_amdgcn_mfma_f32_16x16x32_bf16(ldfrag(mi,0), b0, accS[mi], 0, 0, 0);
            accS[mi] = __builtin_amdgcn_mfma_f32_16x16x32_bf16(ldfrag(mi,1), b1, accS[mi], 0, 0, 0);
        }
        if ((lane & 15) == 0) {
            const float bop = b_op[0];
#pragma unroll
            for (int mi = 0; mi < 4; ++mi)
#pragma unroll
                for (int r = 0; r < 4; ++r) {
                    int m = mi*16 + (lane>>4)*4 + r;
                    sd_lds[wv][m] = sp(accS[mi][r] + bop) * delta;
                }
        }
    }   // accS dead here — only accC (below) lives across the color gather

    // color head: (h) @ Wc, then (+fc+enc) @ Wc accumulated
    floatx4 accC[4];
#pragma unroll
    for (int mi = 0; mi < 4; ++mi) accC[mi] = (floatx4){0.f,0.f,0.f,0.f};
    {
        short8 b0 = ldbfrag(whead, 0, 0);
        short8 b1 = ldbfrag(whead, 0, 1);
#pragma unroll
        for (int mi = 0; mi < 4; ++mi) {
            accC[mi] = __builtin_amdgcn_mfma_f32_16x16x32_bf16(ldfrag(mi,0), b0, accC[mi], 0, 0, 0);
            accC[mi] = __builtin_amdgcn_mfma_f32_16x16x32_bf16(ldfrag(mi,1), b1, accC[mi], 0, 0, 0);
        }
    }

    gather3(3, enc + (size_t)gray*64);   // color features + rays_encoding -> A
    {
        short8 b0 = ldbfrag(whead, 0, 0);
        short8 b1 = ldbfrag(whead, 0, 1);
#pragma unroll
        for (int mi = 0; mi < 4; ++mi) {
            accC[mi] = __builtin_amdgcn_mfma_f32_16x16x32_bf16(ldfrag(mi,0), b0, accC[mi], 0, 0, 0);
            accC[mi] = __builtin_amdgcn_mfma_f32_16x16x32_bf16(ldfrag(mi,1), b1, accC[mi], 0, 0, 0);
        }
    }

    // ---- composite: lane = sample ----
    const float sdv = sd_lds[wv][lane];
    float csd = sdv;
#pragma unroll
    for (int off = 1; off < 64; off <<= 1) {
        float nn = __shfl_up(csd, off, 64);
        if (lane >= off) csd += nn;
    }
    const float nlt = __shfl(csd, 63, 64);
    const float Tw  = __expf(sdv - csd) * (1.f - __expf(-sdv));
    const float em  = __expf(-nlt);
    w_lds[wv][lane] = Tw;

    float rl = Tw * t;
#pragma unroll
    for (int off = 32; off > 0; off >>= 1) rl += __shfl_xor(rl, off, 64);

    // feat[k] = sum_m w_m * (color[m][k] + b_col[k]);  k = lane&15
    const float bcn = b_col[lane & 15];
    float pf = 0.f;
#pragma unroll
    for (int mi = 0; mi < 4; ++mi)
#pragma unroll
        for (int r = 0; r < 4; ++r) {
            int m = mi*16 + (lane>>4)*4 + r;
            pf += w_lds[wv][m] * (accC[mi][r] + bcn);
        }
    pf += __shfl_xor(pf, 16, 64);
    pf += __shfl_xor(pf, 32, 64);

    if (lane < 16)
        out[(size_t)gray*16 + lane] = pf + em * bgc[lane];
    if (lane == 0) {
        out[(size_t)NRAYS*16 + gray] = 1.f - em;   // mask
        out[(size_t)NRAYS*17 + gray] = rl;         // ray_len
    }
}

extern "C" void kernel_launch(void* const* d_in, const int* in_sizes, int n_in,
                              void* d_out, int out_size, void* d_ws, size_t ws_size,
                              hipStream_t stream)
{
    const float* rays    = (const float*)d_in[0];
    const float* centers = (const float*)d_in[1];
    const float* enc     = (const float*)d_in[2];
    const float* nearp   = (const float*)d_in[3];
    const float* farp    = (const float*)d_in[4];
    const float* xy      = (const float*)d_in[5];
    const float* yz      = (const float*)d_in[6];
    const float* zx      = (const float*)d_in[7];
    const float* xyc     = (const float*)d_in[8];
    const float* yzc     = (const float*)d_in[9];
    const float* zxc     = (const float*)d_in[10];
    const float* mlp_w   = (const float*)d_in[11];
    const float* mlp_b   = (const float*)d_in[12];
    const float* w_op    = (const float*)d_in[13];
    const float* b_op    = (const float*)d_in[14];
    const float* w_col   = (const float*)d_in[15];
    const float* b_col   = (const float*)d_in[16];
    const float* bg      = (const float*)d_in[17];
    float* out = (float*)d_out;

    ushort_t* trp = (ushort_t*)d_ws;
    ushort_t* wq  = (ushort_t*)((char*)d_ws + WS_PLANES_BYTES);

    tr_planes<<<6*2*HW_, 256, 0, stream>>>(xy, yz, zx, xyc, yzc, zxc, trp);
    prep_weights<<<(NW_US + 255)/256, 256, 0, stream>>>(mlp_w, w_op, w_col, wq);
    render<<<NRAYS/WV, WV*64, 0, stream>>>(
        rays, centers, enc, nearp, farp, mlp_b, b_op, b_col, bg, trp, wq, out);
}

// Round 6
// 870.561 us; speedup vs baseline: 2.3496x; 2.3496x over previous
//
#include <hip/hip_runtime.h>
#include <hip/hip_bf16.h>

typedef unsigned short ushort_t;
typedef unsigned int   uint_t;
typedef __attribute__((ext_vector_type(8))) short  short8;   // 8 bf16 (4 VGPR)
typedef __attribute__((ext_vector_type(4))) float  floatx4;  // MFMA acc

#define B_    2
#define R_    8192
#define HW_   256
#define S_    64
#define NRAYS (B_*R_)
#define PLANE_ELEMS ((size_t)64*HW_*HW_)
#define TRP_ELEMS   ((size_t)HW_*HW_*64)
#define WS_PLANES_BYTES (6ull*B_*TRP_ELEMS*2)   /* 100,663,296 */
#define NW_US 10240    /* weight ushorts: 8192 mlp + 2048 head */
#define WV 4           /* waves (rays) per block */

__device__ __forceinline__ float bflo(uint_t u){ union{uint_t i;float f;} v; v.i = u << 16;         return v.f; }
__device__ __forceinline__ float bfhi(uint_t u){ union{uint_t i;float f;} v; v.i = u & 0xffff0000u; return v.f; }
__device__ __forceinline__ float sp(float x){ return fmaxf(x, 0.f) + __logf(1.f + __expf(-fabsf(x))); }
__device__ __forceinline__ ushort_t f2bf(float f){
    union{float f;uint_t u;} v; v.f = f;
    uint_t r = v.u + 0x7fffu + ((v.u >> 16) & 1u);   // RTNE
    return (ushort_t)(r >> 16);
}

// ---------------- Kernel A: transpose+quantize planes [C,H,W]f32 -> [H,W,C]bf16 ----------------
__global__ __launch_bounds__(256) void tr_planes(
    const float* __restrict__ p0, const float* __restrict__ p1, const float* __restrict__ p2,
    const float* __restrict__ p3, const float* __restrict__ p4, const float* __restrict__ p5,
    ushort_t* __restrict__ outp)
{
    const int blk = blockIdx.x;
    const int y = blk & 255, b = (blk >> 8) & 1, p = blk >> 9;
    const float* src = (p==0)?p0:(p==1)?p1:(p==2)?p2:(p==3)?p3:(p==4)?p4:p5;
    src += (size_t)b*PLANE_ELEMS + (size_t)y*HW_ + threadIdx.x;
    ushort_t* dst = outp + (size_t)(p*2+b)*TRP_ELEMS + ((size_t)y*HW_ + threadIdx.x)*64;

    __attribute__((aligned(16))) ushort_t tmp[64];
#pragma unroll
    for (int c = 0; c < 64; ++c)
        tmp[c] = f2bf(src[(size_t)c*HW_*HW_]);
#pragma unroll
    for (int k = 0; k < 8; ++k)
        reinterpret_cast<uint4*>(dst)[k] = reinterpret_cast<const uint4*>(tmp)[k];
}

// ---------------- Kernel A2: weights -> bf16, transposed for B-fragments ----------------
// dst layout (ushorts): [0,8192): Wt[l][o][c];  [8192,10240): head[n][c]:
//   n<16: w_col col n;  n==16: w_opacity;  n in 17..31: 0
__global__ __launch_bounds__(256) void prep_weights(
    const float* __restrict__ mlp_w, const float* __restrict__ w_op,
    const float* __restrict__ w_col, ushort_t* __restrict__ dst)
{
    int i = blockIdx.x*256 + threadIdx.x;
    if (i >= NW_US) return;
    float v;
    if (i < 8192) {
        int l = i >> 12, o = (i >> 6) & 63, c = i & 63;
        v = mlp_w[l*4096 + c*64 + o];
    } else {
        int j = i - 8192, n = j >> 6, c = j & 63;
        v = (n < 16) ? w_col[c*16 + n] : (n == 16 ? w_op[c] : 0.f);
    }
    dst[i] = f2bf(v);
}

// ---------------- Kernel B: render (1 wave = 1 ray; MFMA MLP) ----------------
// R5: gather restructured — corner-outer, channel-inner. Each 128 B tap line
// is loaded ONCE (8x dwordx4) and fully consumed into acc[64]. R4's c8-outer
// loop revisited every line 8x16B; with ~21 MB of live lines per XCD vs 4 MB
// L2, each revisit re-fetched: FETCH_SIZE 6.96 GB vs 3.3 GB compulsory.
__global__ __launch_bounds__(256) void render(
    const float* __restrict__ rays, const float* __restrict__ centers,
    const float* __restrict__ enc,  const float* __restrict__ nearp, const float* __restrict__ farp,
    const float* __restrict__ mlp_b, const float* __restrict__ b_op,
    const float* __restrict__ b_col, const float* __restrict__ bgc,
    const ushort_t* __restrict__ trp, const ushort_t* __restrict__ wq,
    float* __restrict__ out)
{
    __shared__ ushort_t A_lds[WV][4096];     // 64 rows x 128B, XOR-swizzled 16B slots
    __shared__ float    sd_lds[WV][64];
    __shared__ float    w_lds [WV][64];

    const int wv = threadIdx.x >> 6, lane = threadIdx.x & 63;
    const int gray = blockIdx.x*WV + wv;
    const int b = gray >> 13;
    ushort_t* A = &A_lds[wv][0];

    const float nr = nearp[gray], fr = farp[gray];
    const float rdx = rays[gray*3+0], rdy = rays[gray*3+1], rdz = rays[gray*3+2];
    const float rox = centers[gray*3+0], roy = centers[gray*3+1], roz = centers[gray*3+2];
    const float delta = (fr - nr) * (1.f/S_);
    const float t  = nr + (fr - nr) * ((lane + 0.5f) * (1.f/S_));
    const float px = rox + t*rdx, py = roy + t*rdy, pz = roz + t*rdz;

    // bilinear prep (shared by density & color planes: same pts)
    int pos[3]; float a00[3], a01[3], a10[3], a11[3];
    {
        float us[3] = {px, py, pz};
        float vs[3] = {py, pz, px};
#pragma unroll
        for (int p = 0; p < 3; ++p) {
            float x = (fminf(fmaxf(us[p],-1.f),1.f) + 1.f) * 127.5f;
            float y = (fminf(fmaxf(vs[p],-1.f),1.f) + 1.f) * 127.5f;
            int x0 = (int)floorf(x); x0 = x0 < 0 ? 0 : (x0 > 254 ? 254 : x0);
            int y0 = (int)floorf(y); y0 = y0 < 0 ? 0 : (y0 > 254 ? 254 : y0);
            float wx = x - (float)x0, wy = y - (float)y0;
            pos[p] = y0*HW_ + x0;
            a00[p] = (1.f-wx)*(1.f-wy); a01[p] = wx*(1.f-wy);
            a10[p] = (1.f-wx)*wy;       a11[p] = wx*wy;
        }
    }

    // gather 3 planes into this lane's A row (m = lane), bf16, swizzled.
    // Per (plane,corner): one full 128 B line load -> 64 FMAs -> next corner.
    auto gather3 = [&](int pbase, const float* encrow) {
        float acc[64];
        if (encrow) {
#pragma unroll
            for (int i = 0; i < 16; ++i) {
                float4 e = *reinterpret_cast<const float4*>(encrow + i*4);
                acc[4*i+0]=e.x; acc[4*i+1]=e.y; acc[4*i+2]=e.z; acc[4*i+3]=e.w;
            }
        } else {
#pragma unroll
            for (int i = 0; i < 64; ++i) acc[i] = 0.f;
        }
#pragma unroll
        for (int p = 0; p < 3; ++p) {
            const ushort_t* base = trp + (size_t)((pbase+p)*2 + b)*TRP_ELEMS + (size_t)pos[p]*64;
#pragma unroll
            for (int corner = 0; corner < 4; ++corner) {
                const ushort_t* cp = base + ((corner & 1) ? 64 : 0) + ((corner & 2) ? 64*HW_ : 0);
                const float w = (corner==0)?a00[p]:(corner==1)?a01[p]:(corner==2)?a10[p]:a11[p];
                union { uint4 v[8]; uint_t u[32]; } q;
#pragma unroll
                for (int k = 0; k < 8; ++k) q.v[k] = reinterpret_cast<const uint4*>(cp)[k];
#pragma unroll
                for (int j = 0; j < 32; ++j) {
                    acc[2*j]   += w * bflo(q.u[j]);
                    acc[2*j+1] += w * bfhi(q.u[j]);
                }
            }
        }
#pragma unroll
        for (int c8 = 0; c8 < 8; ++c8) {
            __attribute__((aligned(16))) ushort_t pk[8];
#pragma unroll
            for (int j = 0; j < 8; ++j) pk[j] = f2bf(acc[c8*8 + j]);
            *reinterpret_cast<uint4*>(reinterpret_cast<char*>(A) + lane*128 + ((c8*16) ^ ((lane&7)<<4)))
                = *reinterpret_cast<const uint4*>(pk);
        }
    };

    // A-fragment load: lane holds row (lane&15) of tile mi, k = kt*32 + (lane>>4)*8 + j
    auto ldfrag = [&](int mi, int kt) -> short8 {
        int m  = mi*16 + (lane&15);
        int cb = (kt*64 + ((lane>>4)*16)) ^ ((m&7)<<4);
        return *reinterpret_cast<const short8*>(reinterpret_cast<const char*>(A) + m*128 + cb);
    };
    // B-fragment: lane holds col (lane&15) of tile nt, k = kt*32 + (lane>>4)*8 + j
    auto ldbfrag = [&](const ushort_t* wrow, int nt, int kt) -> short8 {
        return *reinterpret_cast<const short8*>(wrow + (nt*16 + (lane&15))*64 + kt*32 + (lane>>4)*8);
    };
    // write H value (bf16) at [m][n], swizzled
    auto stH = [&](int m, int n, float v) {
        A[(m*128 + ((n*2) ^ ((m&7)<<4))) >> 1] = f2bf(v);
    };

    // one MLP layer: A(bf16 in LDS) @ Wt -> softplus -> back into A.
    // af[8] preload is a CORRECTNESS requirement: all reads of A must complete
    // before the nt-loop's stH writes overwrite A in place (R3 lesson).
    auto mlp_layer = [&](const ushort_t* wrow, const float* bias) {
        short8 af[8];
#pragma unroll
        for (int mi = 0; mi < 4; ++mi)
#pragma unroll
            for (int kt = 0; kt < 2; ++kt) af[mi*2+kt] = ldfrag(mi, kt);
#pragma unroll
        for (int nt = 0; nt < 4; ++nt) {
            short8 b0 = ldbfrag(wrow, nt, 0);
            short8 b1 = ldbfrag(wrow, nt, 1);
            floatx4 acc[4];
#pragma unroll
            for (int mi = 0; mi < 4; ++mi) {
                acc[mi] = (floatx4){0.f,0.f,0.f,0.f};
                acc[mi] = __builtin_amdgcn_mfma_f32_16x16x32_bf16(af[mi*2+0], b0, acc[mi], 0, 0, 0);
                acc[mi] = __builtin_amdgcn_mfma_f32_16x16x32_bf16(af[mi*2+1], b1, acc[mi], 0, 0, 0);
            }
            const int n = nt*16 + (lane&15);
            const float bc = bias[n];
#pragma unroll
            for (int mi = 0; mi < 4; ++mi)
#pragma unroll
                for (int r = 0; r < 4; ++r) {
                    int m = mi*16 + (lane>>4)*4 + r;
                    stH(m, n, sp(acc[mi][r] + bc));
                }
        }
    };

    // ---- pipeline ----
    gather3(0, nullptr);                 // density features -> A
    mlp_layer(wq,        mlp_b);         // layer 1
    mlp_layer(wq + 4096, mlp_b + 64);    // layer 2  (A now holds h)

    const ushort_t* whead = wq + 8192;

    // sigma head: h @ [w_op | 0...]  (nt=1 tile of head region; col 16 = w_op)
    {
        short8 b0 = ldbfrag(whead, 1, 0);
        short8 b1 = ldbfrag(whead, 1, 1);
        floatx4 accS[4];
#pragma unroll
        for (int mi = 0; mi < 4; ++mi) {
            accS[mi] = (floatx4){0.f,0.f,0.f,0.f};
            accS[mi] = __builtin_amdgcn_mfma_f32_16x16x32_bf16(ldfrag(mi,0), b0, accS[mi], 0, 0, 0);
            accS[mi] = __builtin_amdgcn_mfma_f32_16x16x32_bf16(ldfrag(mi,1), b1, accS[mi], 0, 0, 0);
        }
        if ((lane & 15) == 0) {
            const float bop = b_op[0];
#pragma unroll
            for (int mi = 0; mi < 4; ++mi)
#pragma unroll
                for (int r = 0; r < 4; ++r) {
                    int m = mi*16 + (lane>>4)*4 + r;
                    sd_lds[wv][m] = sp(accS[mi][r] + bop) * delta;
                }
        }
    }   // accS dead here — only accC (below) lives across the color gather

    // color head: (h) @ Wc, then (+fc+enc) @ Wc accumulated
    floatx4 accC[4];
#pragma unroll
    for (int mi = 0; mi < 4; ++mi) accC[mi] = (floatx4){0.f,0.f,0.f,0.f};
    {
        short8 b0 = ldbfrag(whead, 0, 0);
        short8 b1 = ldbfrag(whead, 0, 1);
#pragma unroll
        for (int mi = 0; mi < 4; ++mi) {
            accC[mi] = __builtin_amdgcn_mfma_f32_16x16x32_bf16(ldfrag(mi,0), b0, accC[mi], 0, 0, 0);
            accC[mi] = __builtin_amdgcn_mfma_f32_16x16x32_bf16(ldfrag(mi,1), b1, accC[mi], 0, 0, 0);
        }
    }

    gather3(3, enc + (size_t)gray*64);   // color features + rays_encoding -> A
    {
        short8 b0 = ldbfrag(whead, 0, 0);
        short8 b1 = ldbfrag(whead, 0, 1);
#pragma unroll
        for (int mi = 0; mi < 4; ++mi) {
            accC[mi] = __builtin_amdgcn_mfma_f32_16x16x32_bf16(ldfrag(mi,0), b0, accC[mi], 0, 0, 0);
            accC[mi] = __builtin_amdgcn_mfma_f32_16x16x32_bf16(ldfrag(mi,1), b1, accC[mi], 0, 0, 0);
        }
    }

    // ---- composite: lane = sample ----
    const float sdv = sd_lds[wv][lane];
    float csd = sdv;
#pragma unroll
    for (int off = 1; off < 64; off <<= 1) {
        float nn = __shfl_up(csd, off, 64);
        if (lane >= off) csd += nn;
    }
    const float nlt = __shfl(csd, 63, 64);
    const float Tw  = __expf(sdv - csd) * (1.f - __expf(-sdv));
    const float em  = __expf(-nlt);
    w_lds[wv][lane] = Tw;

    float rl = Tw * t;
#pragma unroll
    for (int off = 32; off > 0; off >>= 1) rl += __shfl_xor(rl, off, 64);

    // feat[k] = sum_m w_m * (color[m][k] + b_col[k]);  k = lane&15
    const float bcn = b_col[lane & 15];
    float pf = 0.f;
#pragma unroll
    for (int mi = 0; mi < 4; ++mi)
#pragma unroll
        for (int r = 0; r < 4; ++r) {
            int m = mi*16 + (lane>>4)*4 + r;
            pf += w_lds[wv][m] * (accC[mi][r] + bcn);
        }
    pf += __shfl_xor(pf, 16, 64);
    pf += __shfl_xor(pf, 32, 64);

    if (lane < 16)
        out[(size_t)gray*16 + lane] = pf + em * bgc[lane];
    if (lane == 0) {
        out[(size_t)NRAYS*16 + gray] = 1.f - em;   // mask
        out[(size_t)NRAYS*17 + gray] = rl;         // ray_len
    }
}

extern "C" void kernel_launch(void* const* d_in, const int* in_sizes, int n_in,
                              void* d_out, int out_size, void* d_ws, size_t ws_size,
                              hipStream_t stream)
{
    const float* rays    = (const float*)d_in[0];
    const float* centers = (const float*)d_in[1];
    const float* enc     = (const float*)d_in[2];
    const float* nearp   = (const float*)d_in[3];
    const float* farp    = (const float*)d_in[4];
    const float* xy      = (const float*)d_in[5];
    const float* yz      = (const float*)d_in[6];
    const float* zx      = (const float*)d_in[7];
    const float* xyc     = (const float*)d_in[8];
    const float* yzc     = (const float*)d_in[9];
    const float* zxc     = (const float*)d_in[10];
    const float* mlp_w   = (const float*)d_in[11];
    const float* mlp_b   = (const float*)d_in[12];
    const float* w_op    = (const float*)d_in[13];
    const float* b_op    = (const float*)d_in[14];
    const float* w_col   = (const float*)d_in[15];
    const float* b_col   = (const float*)d_in[16];
    const float* bg      = (const float*)d_in[17];
    float* out = (float*)d_out;

    ushort_t* trp = (ushort_t*)d_ws;
    ushort_t* wq  = (ushort_t*)((char*)d_ws + WS_PLANES_BYTES);

    tr_planes<<<6*2*HW_, 256, 0, stream>>>(xy, yz, zx, xyc, yzc, zxc, trp);
    prep_weights<<<(NW_US + 255)/256, 256, 0, stream>>>(mlp_w, w_op, w_col, wq);
    render<<<NRAYS/WV, WV*64, 0, stream>>>(
        rays, centers, enc, nearp, farp, mlp_b, b_op, b_col, bg, trp, wq, out);
}